// Round 13
// baseline (228.654 us; speedup 1.0000x reference)
//
#include <hip/hip_runtime.h>

typedef unsigned short u16;
typedef unsigned int   u32;

#define NB   16      // batch
#define NC   128     // channels
#define NPIX 1024    // 32*32
#define NH   4       // heads
#define DH   32      // dim head

typedef __attribute__((ext_vector_type(8))) short short8;
typedef __attribute__((ext_vector_type(4))) float f32x4;
typedef __attribute__((ext_vector_type(8))) _Float16 half8;

#define XROWS 1152   // 64 guard + 1024 + 64 guard rows per batch in xTp

__device__ __forceinline__ float bf2f(u16 u) {
    return __uint_as_float(((u32)u) << 16);
}
__device__ __forceinline__ u16 f2bf(float f) {
    u32 u = __float_as_uint(f);
    u32 r = (u + 0x7fffu + ((u >> 16) & 1u)) >> 16;
    return (u16)r;
}
__device__ __forceinline__ u16 f2h(float f) {
    _Float16 h = (_Float16)f;
    u16 r; __builtin_memcpy(&r, &h, 2); return r;
}
__device__ __forceinline__ int pk_h2(float a, float b) {
    auto h = __builtin_amdgcn_cvt_pkrtz(a, b);   // __fp16 ext_vector(2)
    int r; __builtin_memcpy(&r, &h, 4); return r;
}
// dtype-agnostic loads: isf=1 -> fp32 data, isf=0 -> bf16 data
__device__ __forceinline__ float loadf(const void* p, int i, int isf) {
    return isf ? ((const float*)p)[i] : bf2f(((const u16*)p)[i]);
}
__device__ __forceinline__ float4 load4(const void* p, int i4, int isf) {
    if (isf) return ((const float4*)p)[i4];
    ushort4 u = ((const ushort4*)p)[i4];
    return make_float4(bf2f(u.x), bf2f(u.y), bf2f(u.z), bf2f(u.w));
}

// ---------------------------------------------------------------------------
// Kernel D: dtype detector (proven).
// ---------------------------------------------------------------------------
__global__ __launch_bounds__(256) void detect_kernel(
        const void* __restrict__ x, int* __restrict__ flag) {
    __shared__ int cnt;
    if (threadIdx.x == 0) cnt = 0;
    __syncthreads();
    const u16* p = (const u16*)x;
    int c = 0;
    for (int i = threadIdx.x; i < 4096; i += 256) {
        int e = (p[i] >> 7) & 0xFF;
        if (e >= 134) ++c;
    }
    atomicAdd(&cnt, c);
    __syncthreads();
    if (threadIdx.x == 0) flag[0] = (cnt > 100) ? 1 : 0;
}

// ---------------------------------------------------------------------------
// prep_wall: merged weight prep (proven round 12).
// ---------------------------------------------------------------------------
__global__ __launch_bounds__(256) void prep_wall(
        const void* __restrict__ w0, const void* __restrict__ w1,
        const void* __restrict__ w2, const void* __restrict__ ow,
        u16* __restrict__ Wt, u16* __restrict__ Wf,
        const int* __restrict__ flag) {
    int isf = flag[0];
    int i = blockIdx.x * 256 + threadIdx.x;
    if (i < 442368) {
        int j   = i / 147456;
        int rr  = i % 147456;
        int tap = rr >> 14;
        int co  = (rr >> 7) & 127;
        int ci  = rr & 127;
        const void* w = (j == 0) ? w0 : ((j == 1) ? w1 : w2);
        float v = loadf(w, (co * 128 + ci) * 9 + tap, isf);
        Wt[i] = f2bf(v);
    } else {
        int i2 = i - 442368;
        if (i2 < 16384) Wf[i2] = f2h(loadf(ow, i2, isf));
    }
}

// ---------------------------------------------------------------------------
// prep_x: xTp[b][64+pix][ci] bf16 + guard zeroing (proven round 12).
// grid (8 pixg, 4 cig, 16 b)
// ---------------------------------------------------------------------------
__global__ __launch_bounds__(256) void prep_x(
        const void* __restrict__ x, u16* __restrict__ xTp,
        const int* __restrict__ flag) {
    __shared__ float tile[32 * 129];
    int isf = flag[0];
    int t = threadIdx.x;
    int pixg = blockIdx.x, cig = blockIdx.y, b = blockIdx.z;

    if (pixg == 0 || pixg == 7) {
        int row = (pixg == 0 ? 0 : 1088) + (t >> 2);
        int seg = t & 3;
        size_t dst = ((size_t)(b * XROWS + row)) * 128 + cig * 32 + seg * 8;
        *(uint4*)&xTp[dst] = make_uint4(0, 0, 0, 0);
    }

    int ci = t >> 3, px0 = (t & 7) * 16;
    int base = b * (NC * NPIX) + (cig * 32 + ci) * NPIX + pixg * 128 + px0;
#pragma unroll
    for (int u = 0; u < 4; ++u) {
        float4 v = load4(x, (base >> 2) + u, isf);
        float* d = &tile[ci * 129 + px0 + u * 4];
        d[0] = v.x; d[1] = v.y; d[2] = v.z; d[3] = v.w;
    }
    __syncthreads();
#pragma unroll
    for (int u = 0; u < 2; ++u) {
        int c = t + u * 256;
        int pix = c >> 2, seg = c & 3;
        u16 tmp[8];
#pragma unroll
        for (int e = 0; e < 8; ++e)
            tmp[e] = f2bf(tile[(seg * 8 + e) * 129 + pix]);
        size_t dst = ((size_t)(b * XROWS + 64 + pixg * 128 + pix)) * 128
                   + cig * 32 + seg * 8;
        *(ushort4*)&xTp[dst]     = make_ushort4(tmp[0], tmp[1], tmp[2], tmp[3]);
        *(ushort4*)&xTp[dst + 4] = make_ushort4(tmp[4], tmp[5], tmp[6], tmp[7]);
    }
}

// ---------------------------------------------------------------------------
// conv7: conv6 + explicit register double-buffer software pipeline.
// grid (8 pt, 16 b, 3 j) = 384 blocks; block 128co x 128pix; wave 64x64.
// LDS = Xh only (49.7 KB). Flattened 36-step K-loop (tap*4+ks), fully
// unrolled, ping-pong A/B register buffers: step s issues step s+1's
// 4 global A-loads + 4 LDS B-reads BEFORE its 16 MFMAs, so the ~310-cyc
// MFMA block covers L2/LDS latency (conv6's VGPR=92 showed the compiler
// allocated no prefetch buffers -> per-step latency stall, MfmaUtil 10%).
// ---------------------------------------------------------------------------
__global__ __launch_bounds__(256) void conv7_kernel(
        const u16* __restrict__ xTp, const u16* __restrict__ Wt,
        float* __restrict__ conv_out, float* __restrict__ stats) {
    __shared__ __align__(16) u16 Xh[194 * 128];   // 49,664 B

    int t = threadIdx.x;
    int pt = blockIdx.x, b = blockIdx.y, j = blockIdx.z;
    int p0 = pt * 128;
    int w = t >> 6, lane = t & 63;
    int q = lane >> 4, l16 = lane & 15;
    int cobase = (w & 1) * 64;
    int pixbase = (w >> 1) * 64;

    const u16* xb  = xTp + ((size_t)b * XROWS + 64) * 128;  // row 0 = pixel 0
    const u16* wjb = Wt + (size_t)j * 9 * 16384;

    // ---- stage Xh rows [p0-33, p0+161), unconditional (guard rows) ----
#pragma unroll
    for (int k = 0; k < 13; ++k) {
        int c = t + k * 256;
        if (c < 194 * 16) {
            int row = c >> 4, seg = c & 15;
            int pg = p0 - 33 + row;
            uint4 v = *(const uint4*)(xb + (size_t)pg * 128 + seg * 8);
            *(uint4*)&Xh[row * 128 + ((seg + row) & 15) * 8] = v;
        }
    }
    __syncthreads();     // the only barrier in the kernel

    f32x4 acc[4][4];
#pragma unroll
    for (int mt = 0; mt < 4; ++mt)
#pragma unroll
        for (int nt = 0; nt < 4; ++nt) acc[mt][nt] = (f32x4)0.f;

#define LOAD_A(TAP, KS, A)                                                    \
    {                                                                         \
        const u16* wt_ = wjb + (TAP) * 16384;                                 \
        int k0_ = (KS) * 32 + q * 8;                                          \
        _Pragma("unroll")                                                     \
        for (int mt = 0; mt < 4; ++mt)                                        \
            (A)[mt] = *(const short8*)(wt_                                    \
                      + (size_t)(cobase + mt * 16 + l16) * 128 + k0_);        \
    }
#define LOAD_B(TAP, KS, B)                                                    \
    {                                                                         \
        int dy_ = (TAP) / 3, dx_ = (TAP) % 3;                                 \
        bool ie_ = (dx_ == 0) && (l16 == 0);                                  \
        bool io_ = (dx_ == 2) && (l16 == 15);                                 \
        int rb_ = pixbase + dy_ * 32 + dx_ + l16;                             \
        int sl_ = (KS) * 4 + q;                                               \
        _Pragma("unroll")                                                     \
        for (int nt = 0; nt < 4; ++nt) {                                      \
            int row_ = rb_ + nt * 16;                                         \
            short8 v_ = *(const short8*)&Xh[row_ * 128                        \
                                            + ((sl_ + row_) & 15) * 8];       \
            (B)[nt] = ((nt & 1) ? io_ : ie_) ? (short8)0 : v_;                \
        }                                                                     \
    }

    short8 aB[2][4], bB[2][4];
    LOAD_A(0, 0, aB[0]);
    LOAD_B(0, 0, bB[0]);
#pragma unroll
    for (int s = 0; s < 36; ++s) {
        int cur = s & 1, nxt = cur ^ 1;
        if (s < 35) {
            int sn = s + 1;
            LOAD_A(sn >> 2, sn & 3, aB[nxt]);
            LOAD_B(sn >> 2, sn & 3, bB[nxt]);
        }
#pragma unroll
        for (int mt = 0; mt < 4; ++mt)
#pragma unroll
            for (int nt = 0; nt < 4; ++nt)
                acc[mt][nt] = __builtin_amdgcn_mfma_f32_16x16x32_bf16(
                    aB[cur][mt], bB[cur][nt], acc[mt][nt], 0, 0, 0);
    }
#undef LOAD_A
#undef LOAD_B

    // ---- epilogue: conv_out [j*16+b][co][pix] fp32 + stats (proven) ----
    float s = 0.f, s2 = 0.f;
    size_t obase = ((size_t)(j * NB + b) * NC) * NPIX;
#pragma unroll
    for (int mt = 0; mt < 4; ++mt) {
#pragma unroll
        for (int nt = 0; nt < 4; ++nt) {
            f32x4 v = acc[mt][nt];
            int co  = cobase + mt * 16 + q * 4;
            int pix = p0 + pixbase + nt * 16 + l16;
#pragma unroll
            for (int r = 0; r < 4; ++r) {
                float val = v[r];
                conv_out[obase + (size_t)(co + r) * NPIX + pix] = val;
                s += val;
                s2 = fmaf(val, val, s2);
            }
        }
    }
#pragma unroll
    for (int off = 32; off; off >>= 1) {
        s  += __shfl_down(s,  (unsigned)off, 64);
        s2 += __shfl_down(s2, (unsigned)off, 64);
    }
    if (lane == 0) {
        atomicAdd(&stats[(j * NB + b) * 2 + 0], s);
        atomicAdd(&stats[(j * NB + b) * 2 + 1], s2);
    }
}

// ---------------------------------------------------------------------------
// norm_kernel: GroupNorm(1) + exact GELU. Outputs f16 (proven round 7)
// ---------------------------------------------------------------------------
__global__ __launch_bounds__(256) void norm_kernel(
        const float* __restrict__ conv_out, const float* __restrict__ stats,
        const void* __restrict__ g0, const void* __restrict__ b0,
        const void* __restrict__ g1, const void* __restrict__ b1,
        const void* __restrict__ g2, const void* __restrict__ b2,
        u16* __restrict__ qh, u16* __restrict__ kh, u16* __restrict__ vh,
        const int* __restrict__ flag) {
    __shared__ float tile[32 * 257];
    int isf = flag[0];
    int t = threadIdx.x;
    int n0 = blockIdx.x * 256;
    int h = blockIdx.y;
    int z = blockIdx.z;
    int j = z >> 4;
    int b = z & 15;
    const void* gam = (j == 0) ? g0 : ((j == 1) ? g1 : g2);
    const void* bet = (j == 0) ? b0 : ((j == 1) ? b1 : b2);

    float sum = stats[z * 2], ss = stats[z * 2 + 1];
    const float inv = 1.0f / 131072.0f;
    float mean = sum * inv;
    float var  = fmaxf(ss * inv - mean * mean, 0.f);
    float rstd = rsqrtf(var + 1e-6f);

    const float* src = conv_out + ((size_t)z * NC + h * DH) * NPIX + n0;

    if (j == 2) {
        u16* dst = vh + (((size_t)(b * NH + h)) * DH) * NPIX + n0;
#pragma unroll
        for (int cl = 0; cl < 32; ++cl) {
            float v = src[cl * NPIX + t];
            v = (v - mean) * rstd * loadf(gam, h * DH + cl, isf)
              + loadf(bet, h * DH + cl, isf);
            v = 0.5f * v * (1.0f + erff(v * 0.70710678118654752f));
            dst[(size_t)cl * NPIX + t] = f2h(v);
        }
        return;
    }

#pragma unroll
    for (int cl = 0; cl < 32; ++cl) tile[cl * 257 + t] = src[cl * NPIX + t];
    __syncthreads();

    u16* dst = ((j == 0) ? qh : kh)
             + (((size_t)(b * NH + h)) * NPIX + n0) * DH;
#pragma unroll
    for (int k = 0; k < 32; ++k) {
        int o = t + k * 256;
        int d = o & 31, nl = o >> 5;
        float v = tile[d * 257 + nl];
        v = (v - mean) * rstd * loadf(gam, h * DH + d, isf)
          + loadf(bet, h * DH + d, isf);
        v = 0.5f * v * (1.0f + erff(v * 0.70710678118654752f));
        dst[o] = f2h(v);
    }
}

// ---------------------------------------------------------------------------
// bias_t kernel: biasT[h][m][n] = table[rel[n*1024+m]][h]  (bf16, proven)
// ---------------------------------------------------------------------------
__global__ __launch_bounds__(256) void biasT_kernel(
        const int* __restrict__ rel, const void* __restrict__ table,
        u16* __restrict__ biasT, const int* __restrict__ flag) {
    __shared__ int rl[64 * 65];
    int isf = flag[0];
    int t = threadIdx.x;
    int nt = blockIdx.x, mt = blockIdx.y;

#pragma unroll
    for (int c = 0; c < 16; ++c) {
        int i = t + c * 256;              // 4096
        int r = i >> 6, cc = i & 63;      // r=n-local, cc=m-local
        rl[r * 65 + cc] = rel[(size_t)(nt * 64 + r) * 1024 + mt * 64 + cc];
    }
    __syncthreads();

#pragma unroll
    for (int h = 0; h < NH; ++h) {
#pragma unroll
        for (int c = 0; c < 16; ++c) {
            int wdx = t + c * 256;        // 4096
            int m = wdx >> 6, n = wdx & 63;
            int ri = rl[n * 65 + m];
            float v = loadf(table, ri * NH + h, isf);
            biasT[((size_t)h << 20) + (size_t)(mt * 64 + m) * 1024
                  + nt * 64 + n] = f2bf(v);
        }
    }
}

// ---------------------------------------------------------------------------
// attn2: MFMA flash attention, zero LDS (proven round 7/8).
// ---------------------------------------------------------------------------
__global__ __launch_bounds__(256) void attn2_kernel(
        const u16* __restrict__ qh, const u16* __restrict__ kh,
        const u16* __restrict__ vh, const u16* __restrict__ biasT,
        u16* __restrict__ attfh) {
    int t = threadIdx.x;
    int b = blockIdx.x, h = blockIdx.y, qt = blockIdx.z;
    int w = t >> 6, lane = t & 63, q = lane >> 4, l16 = lane & 15;
    int nrow0 = qt * 128 + w * 32;

    const u16* qb = qh + (((size_t)(b * NH + h)) * NPIX) * DH;
    const u16* kb = kh + (((size_t)(b * NH + h)) * NPIX) * DH;
    const u16* vb = vh + (((size_t)(b * NH + h)) * DH) * NPIX;
    const u16* bb = biasT + ((size_t)h << 20);

    half8 qf[2];
#pragma unroll
    for (int nt = 0; nt < 2; ++nt)
        qf[nt] = *(const half8*)(qb + (size_t)(nrow0 + nt * 16 + l16) * DH
                                 + q * 8);

    f32x4 O[2][2];   // [dt][nt], O^T C-layout: col n=l16, row d=q*4+reg
#pragma unroll
    for (int dt = 0; dt < 2; ++dt)
#pragma unroll
        for (int nt = 0; nt < 2; ++nt) O[dt][nt] = (f32x4)0.f;
    float mrow[2] = {-1e30f, -1e30f}, lrow[2] = {0.f, 0.f};

    int addrLo = ((2 * (q & 1)) * 16 + l16) * 4;
    int addrHi = addrLo + 64;
    bool hiQ = (q >= 2);

    for (int kc = 0; kc < 8; ++kc) {
        int m0 = kc * 128;
        f32x4 St[8][2];
#pragma unroll
        for (int mt = 0; mt < 8; ++mt) {
            half8 kf = *(const half8*)(kb + (size_t)(m0 + mt * 16 + l16) * DH
                                       + q * 8);
            St[mt][0] = __builtin_amdgcn_mfma_f32_16x16x32_f16(
                kf, qf[0], (f32x4)0.f, 0, 0, 0);
            St[mt][1] = __builtin_amdgcn_mfma_f32_16x16x32_f16(
                kf, qf[1], (f32x4)0.f, 0, 0, 0);
        }
        float mx[2] = {-1e30f, -1e30f};
#pragma unroll
        for (int mt = 0; mt < 8; ++mt)
#pragma unroll
            for (int nt = 0; nt < 2; ++nt) {
                const u16* bp = bb + (size_t)(m0 + mt * 16 + q * 4) * 1024
                              + nrow0 + nt * 16 + l16;
#pragma unroll
                for (int r = 0; r < 4; ++r) {
                    float v = St[mt][nt][r] + bf2f(bp[(size_t)r * 1024]);
                    St[mt][nt][r] = v;
                    mx[nt] = fmaxf(mx[nt], v);
                }
            }
        float alpha[2];
#pragma unroll
        for (int nt = 0; nt < 2; ++nt) {
            mx[nt] = fmaxf(mx[nt], __shfl_xor(mx[nt], 16, 64));
            mx[nt] = fmaxf(mx[nt], __shfl_xor(mx[nt], 32, 64));
            float mn = fmaxf(mrow[nt], mx[nt]);
            alpha[nt] = __expf(mrow[nt] - mn);
            mrow[nt] = mn;
        }
        float sm[2] = {0.f, 0.f};
#pragma unroll
        for (int mt = 0; mt < 8; ++mt)
#pragma unroll
            for (int nt = 0; nt < 2; ++nt)
#pragma unroll
                for (int r = 0; r < 4; ++r) {
                    float p = __expf(St[mt][nt][r] - mrow[nt]);
                    St[mt][nt][r] = p;
                    sm[nt] += p;
                }
#pragma unroll
        for (int nt = 0; nt < 2; ++nt) {
            sm[nt] += __shfl_xor(sm[nt], 16, 64);
            sm[nt] += __shfl_xor(sm[nt], 32, 64);
            lrow[nt] = lrow[nt] * alpha[nt] + sm[nt];
        }
#pragma unroll
        for (int dt = 0; dt < 2; ++dt)
#pragma unroll
            for (int nt = 0; nt < 2; ++nt)
#pragma unroll
                for (int r = 0; r < 4; ++r)
                    O[dt][nt][r] *= alpha[nt];
#pragma unroll
        for (int ms = 0; ms < 4; ++ms) {
            half8 vf[2];
#pragma unroll
            for (int dt = 0; dt < 2; ++dt)
                vf[dt] = *(const half8*)(vb + (size_t)(dt * 16 + l16) * NPIX
                                         + m0 + ms * 32 + q * 8);
#pragma unroll
            for (int nt = 0; nt < 2; ++nt) {
                int p01_0 = pk_h2(St[2 * ms][nt][0],     St[2 * ms][nt][1]);
                int p23_0 = pk_h2(St[2 * ms][nt][2],     St[2 * ms][nt][3]);
                int p01_1 = pk_h2(St[2 * ms + 1][nt][0], St[2 * ms + 1][nt][1]);
                int p23_1 = pk_h2(St[2 * ms + 1][nt][2], St[2 * ms + 1][nt][3]);
                // FULL-EXEC bpermutes, then per-dest select (round-7 fix).
                int a0 = __builtin_amdgcn_ds_bpermute(addrLo, p01_0);
                int a1 = __builtin_amdgcn_ds_bpermute(addrLo, p23_0);
                int a2 = __builtin_amdgcn_ds_bpermute(addrHi, p01_0);
                int a3 = __builtin_amdgcn_ds_bpermute(addrHi, p23_0);
                int b0 = __builtin_amdgcn_ds_bpermute(addrLo, p01_1);
                int b1 = __builtin_amdgcn_ds_bpermute(addrLo, p23_1);
                int b2 = __builtin_amdgcn_ds_bpermute(addrHi, p01_1);
                int b3 = __builtin_amdgcn_ds_bpermute(addrHi, p23_1);
                int pb[4];
                pb[0] = hiQ ? b0 : a0;
                pb[1] = hiQ ? b1 : a1;
                pb[2] = hiQ ? b2 : a2;
                pb[3] = hiQ ? b3 : a3;
                half8 pf; __builtin_memcpy(&pf, pb, 16);
#pragma unroll
                for (int dt = 0; dt < 2; ++dt)
                    O[dt][nt] = __builtin_amdgcn_mfma_f32_16x16x32_f16(
                        vf[dt], pf, O[dt][nt], 0, 0, 0);
            }
        }
    }

    // ---- epilogue: attfh[b][n][c] f16 (8B packed stores) ----
#pragma unroll
    for (int nt = 0; nt < 2; ++nt) {
        float rl = 1.0f / lrow[nt];
        int n = nrow0 + nt * 16 + l16;
        u16* dst = attfh + ((size_t)b * NPIX + n) * NC + h * DH;
#pragma unroll
        for (int dt = 0; dt < 2; ++dt) {
            f32x4 o = O[dt][nt];
            uint2 pv = make_uint2((u32)pk_h2(o[0] * rl, o[1] * rl),
                                  (u32)pk_h2(o[2] * rl, o[3] * rl));
            *(uint2*)(dst + dt * 16 + q * 4) = pv;
        }
    }
}

// ---------------------------------------------------------------------------
// out3: MFMA 1x1 conv + bias, zero LDS (proven round 8).
// ---------------------------------------------------------------------------
__global__ __launch_bounds__(256) void out3_kernel(
        const u16* __restrict__ attfh, const u16* __restrict__ Wf,
        const void* __restrict__ ob, void* __restrict__ out,
        const int* __restrict__ flag) {
    int isf = flag[0];
    int t = threadIdx.x;
    int n0 = blockIdx.x * 64, b = blockIdx.y;
    int w = t >> 6, lane = t & 63, q = lane >> 4, l16 = lane & 15;
    int cobase = (w & 1) * 64, nbase = (w >> 1) * 32;

    f32x4 acc[4][2];
#pragma unroll
    for (int mt = 0; mt < 4; ++mt)
#pragma unroll
        for (int nt = 0; nt < 2; ++nt) acc[mt][nt] = (f32x4)0.f;

    const u16* ab = attfh + ((size_t)b * NPIX + n0 + nbase) * NC;
#pragma unroll
    for (int ks = 0; ks < 4; ++ks) {
        int k0 = ks * 32 + q * 8;
        half8 a[4], bfr[2];
#pragma unroll
        for (int mt = 0; mt < 4; ++mt)
            a[mt] = *(const half8*)(Wf + (size_t)(cobase + mt * 16 + l16) * NC
                                    + k0);
#pragma unroll
        for (int nt = 0; nt < 2; ++nt)
            bfr[nt] = *(const half8*)(ab + (size_t)(nt * 16 + l16) * NC + k0);
#pragma unroll
        for (int mt = 0; mt < 4; ++mt)
#pragma unroll
            for (int nt = 0; nt < 2; ++nt)
                acc[mt][nt] = __builtin_amdgcn_mfma_f32_16x16x32_f16(
                    a[mt], bfr[nt], acc[mt][nt], 0, 0, 0);
    }

#pragma unroll
    for (int mt = 0; mt < 4; ++mt) {
#pragma unroll
        for (int nt = 0; nt < 2; ++nt) {
            f32x4 v = acc[mt][nt];
            int n = n0 + nbase + nt * 16 + l16;
#pragma unroll
            for (int r = 0; r < 4; ++r) {
                int co = cobase + mt * 16 + q * 4 + r;
                float val = v[r] + loadf(ob, co, isf);
                size_t oidx = ((size_t)b * NC + co) * NPIX + n;
                if (isf) ((float*)out)[oidx] = val;
                else     ((u16*)out)[oidx]   = f2bf(val);
            }
        }
    }
}

// ---------------------------------------------------------------------------
// Workspace (peak ~48 MiB, lifetime aliasing):
//   [0,448) stats | [448,452) flag
//   regQ = ws+512 (25,165,824 B):
//     xTp bf16 4,718,592 B @Q+0 (guards zeroed by prep_x)
//     Wt  bf16 884,736 B  @Q+5242880                 (prep_wall -> conv7)
//     then qh f16 4 MB @Q+0, kh @Q+4M, vh @Q+8M      (norm -> attn2)
//     Wf f16 32 KB @Q+16777216                        (prep_wall -> out3)
//   regA = regQ+25165824 (25,165,824 B):
//     conv fp32 25 MB                                 (conv7 -> norm)
//     then biasT bf16 8 MB @A+0, attfh f16 4 MB @A+8388608
// Order: memset stats -> detect -> prep_wall -> prep_x -> conv7 -> norm ->
//        biasT -> attn2 -> out3
// ---------------------------------------------------------------------------
extern "C" void kernel_launch(void* const* d_in, const int* in_sizes, int n_in,
                              void* d_out, int out_size, void* d_ws,
                              size_t ws_size, hipStream_t stream) {
    (void)in_sizes; (void)n_in; (void)out_size; (void)ws_size;
    const void* x     = d_in[0];
    const void* wq    = d_in[1];
    const void* gq    = d_in[2];
    const void* bq    = d_in[3];
    const void* wk    = d_in[4];
    const void* gk    = d_in[5];
    const void* bk    = d_in[6];
    const void* wv    = d_in[7];
    const void* gv    = d_in[8];
    const void* bv    = d_in[9];
    const void* table = d_in[10];
    const int*  rel   = (const int*)d_in[11];
    const void* ow    = d_in[12];
    const void* ob    = d_in[13];

    char* ws = (char*)d_ws;
    float* stats = (float*)(ws);
    int*   flag  = (int*)(ws + 448);
    char*  regQ  = ws + 512;
    u16*   xTp   = (u16*)regQ;                       // padded, 4,718,592 B
    u16*   Wt    = (u16*)(regQ + 5242880);
    u16*   qhp   = (u16*)regQ;                       // alias after conv7
    u16*   khp   = (u16*)(regQ + 4194304);
    u16*   vhp   = (u16*)(regQ + 8388608);
    u16*   Wf    = (u16*)(regQ + 16777216);          // prep_wall -> out3
    char*  regA  = regQ + 25165824;
    float* conv  = (float*)regA;                     // conv7 -> norm
    u16*   biasT = (u16*)regA;                       // alias after norm
    u16*   attfh = (u16*)(regA + 8388608);           // attn2 -> out3 (f16)

    (void)hipMemsetAsync(stats, 0, 96 * sizeof(float), stream);
    detect_kernel<<<1, 256, 0, stream>>>(x, flag);
    prep_wall<<<1793, 256, 0, stream>>>(wq, wk, wv, ow, Wt, Wf, flag);
    prep_x<<<dim3(8, 4, 16), 256, 0, stream>>>(x, xTp, flag);
    conv7_kernel<<<dim3(8, 16, 3), 256, 0, stream>>>(xTp, Wt, conv, stats);
    norm_kernel<<<dim3(4, 4, 48), 256, 0, stream>>>(conv, stats,
                                                    gq, bq, gk, bk, gv, bv,
                                                    qhp, khp, vhp, flag);
    biasT_kernel<<<dim3(16, 16), 256, 0, stream>>>(rel, table, biasT, flag);
    attn2_kernel<<<dim3(16, 4, 8), 256, 0, stream>>>(qhp, khp, vhp, biasT,
                                                     attfh);
    out3_kernel<<<dim3(16, 16), 256, 0, stream>>>(attfh, Wf, ob, d_out, flag);
}

// Round 14
// 213.927 us; speedup vs baseline: 1.0688x; 1.0688x over previous
//
#include <hip/hip_runtime.h>

typedef unsigned short u16;
typedef unsigned int   u32;

#define NB   16      // batch
#define NC   128     // channels
#define NPIX 1024    // 32*32
#define NH   4       // heads
#define DH   32      // dim head

typedef __attribute__((ext_vector_type(8))) short short8;
typedef __attribute__((ext_vector_type(4))) float f32x4;
typedef __attribute__((ext_vector_type(8))) _Float16 half8;

#define XROWS 1152   // 64 guard + 1024 + 64 guard rows per batch in xTp

__device__ __forceinline__ float bf2f(u16 u) {
    return __uint_as_float(((u32)u) << 16);
}
__device__ __forceinline__ u16 f2bf(float f) {
    u32 u = __float_as_uint(f);
    u32 r = (u + 0x7fffu + ((u >> 16) & 1u)) >> 16;
    return (u16)r;
}
__device__ __forceinline__ u16 f2h(float f) {
    _Float16 h = (_Float16)f;
    u16 r; __builtin_memcpy(&r, &h, 2); return r;
}
__device__ __forceinline__ int pk_h2(float a, float b) {
    auto h = __builtin_amdgcn_cvt_pkrtz(a, b);   // __fp16 ext_vector(2)
    int r; __builtin_memcpy(&r, &h, 4); return r;
}
// dtype-agnostic loads: isf=1 -> fp32 data, isf=0 -> bf16 data
__device__ __forceinline__ float loadf(const void* p, int i, int isf) {
    return isf ? ((const float*)p)[i] : bf2f(((const u16*)p)[i]);
}
__device__ __forceinline__ float4 load4(const void* p, int i4, int isf) {
    if (isf) return ((const float4*)p)[i4];
    ushort4 u = ((const ushort4*)p)[i4];
    return make_float4(bf2f(u.x), bf2f(u.y), bf2f(u.z), bf2f(u.w));
}
// Per-wave dtype self-detect (replaces detect_kernel dispatch).
// fp32 N(0,1) data: the 32 low-mantissa halfwords in x[0..63] hit exp>=134
// with P~0.48 each (P(no hit)=0.52^32~8e-10, identical for every wave since
// all read the same words). bf16 N(0,1): |x|<128 -> exp<134 always.
__device__ __forceinline__ int detect_isf(const void* x) {
    const u16* p = (const u16*)x;
    u16 v = p[threadIdx.x & 63];
    int e = (v >> 7) & 0xFF;
    unsigned long long m = __ballot(e >= 134);
    return m != 0ull ? 1 : 0;
}

// ---------------------------------------------------------------------------
// prep_all: fused prep (was detect + prep_wall + prep_x + biasT + memset).
// 1D grid of 2560 blocks:
//   [0,1792):    Wt/Wf weight prep (+ block 0 zeroes stats)
//   [1792,2304): xTp transpose + guard zeroing (512 = 8 pixg x 4 cig x 16 b)
//   [2304,2560): biasT transpose-gather   (256 = 16 nt x 16 mt)
// ---------------------------------------------------------------------------
__global__ __launch_bounds__(256) void prep_all(
        const void* __restrict__ x,
        const void* __restrict__ w0, const void* __restrict__ w1,
        const void* __restrict__ w2, const void* __restrict__ ow,
        const int* __restrict__ rel, const void* __restrict__ table,
        u16* __restrict__ Wt, u16* __restrict__ Wf, u16* __restrict__ xTp,
        u16* __restrict__ biasT, float* __restrict__ stats) {
    __shared__ __align__(16) u32 smem_u[4160];   // 16,640 B union
    int isf = detect_isf(x);
    int bid = blockIdx.x;
    int t = threadIdx.x;

    if (bid < 1792) {
        // ---- weight prep (proven prep_wall) + stats zeroing ----
        if (bid == 0 && t < 96) stats[t] = 0.f;
        int i = bid * 256 + t;
        if (i < 442368) {
            int j   = i / 147456;
            int rr  = i % 147456;
            int tap = rr >> 14;
            int co  = (rr >> 7) & 127;
            int ci  = rr & 127;
            const void* w = (j == 0) ? w0 : ((j == 1) ? w1 : w2);
            float v = loadf(w, (co * 128 + ci) * 9 + tap, isf);
            Wt[i] = f2bf(v);
        } else {
            int i2 = i - 442368;
            if (i2 < 16384) Wf[i2] = f2h(loadf(ow, i2, isf));
        }
    } else if (bid < 2304) {
        // ---- xTp transpose + guard zeroing (proven prep_x) ----
        float* tile = (float*)smem_u;            // 32*129 floats
        int b2 = bid - 1792;
        int pixg = b2 & 7, cig = (b2 >> 3) & 3, b = b2 >> 5;

        if (pixg == 0 || pixg == 7) {
            int row = (pixg == 0 ? 0 : 1088) + (t >> 2);
            int seg = t & 3;
            size_t dst = ((size_t)(b * XROWS + row)) * 128 + cig * 32 + seg * 8;
            *(uint4*)&xTp[dst] = make_uint4(0, 0, 0, 0);
        }

        int ci = t >> 3, px0 = (t & 7) * 16;
        int base = b * (NC * NPIX) + (cig * 32 + ci) * NPIX + pixg * 128 + px0;
#pragma unroll
        for (int u = 0; u < 4; ++u) {
            float4 v = load4(x, (base >> 2) + u, isf);
            float* d = &tile[ci * 129 + px0 + u * 4];
            d[0] = v.x; d[1] = v.y; d[2] = v.z; d[3] = v.w;
        }
        __syncthreads();
#pragma unroll
        for (int u = 0; u < 2; ++u) {
            int c = t + u * 256;
            int pix = c >> 2, seg = c & 3;
            u16 tmp[8];
#pragma unroll
            for (int e = 0; e < 8; ++e)
                tmp[e] = f2bf(tile[(seg * 8 + e) * 129 + pix]);
            size_t dst = ((size_t)(b * XROWS + 64 + pixg * 128 + pix)) * 128
                       + cig * 32 + seg * 8;
            *(ushort4*)&xTp[dst] =
                make_ushort4(tmp[0], tmp[1], tmp[2], tmp[3]);
            *(ushort4*)&xTp[dst + 4] =
                make_ushort4(tmp[4], tmp[5], tmp[6], tmp[7]);
        }
    } else {
        // ---- biasT[h][m][n] transpose-gather (proven biasT_kernel) ----
        int* rl = (int*)smem_u;                  // 64*65 ints
        int b2 = bid - 2304;
        int nt = b2 & 15, mt = b2 >> 4;

#pragma unroll
        for (int c = 0; c < 16; ++c) {
            int i = t + c * 256;              // 4096
            int r = i >> 6, cc = i & 63;      // r=n-local, cc=m-local
            rl[r * 65 + cc] = rel[(size_t)(nt * 64 + r) * 1024 + mt * 64 + cc];
        }
        __syncthreads();

#pragma unroll
        for (int h = 0; h < NH; ++h) {
#pragma unroll
            for (int c = 0; c < 16; ++c) {
                int wdx = t + c * 256;        // 4096
                int m = wdx >> 6, n = wdx & 63;
                int ri = rl[n * 65 + m];
                float v = loadf(table, ri * NH + h, isf);
                biasT[((size_t)h << 20) + (size_t)(mt * 64 + m) * 1024
                      + nt * 64 + n] = f2bf(v);
            }
        }
    }
}

// ---------------------------------------------------------------------------
// conv6: MFMA implicit-GEMM 3x3 conv — B (pixels) via LDS, A (weights)
// direct global->VGPR, ZERO K-loop barriers (proven round 12, 51 us).
// grid (8 pt, 16 b, 3 j) = 384 blocks; block 128co x 128pix; wave 64x64.
// ---------------------------------------------------------------------------
__global__ __launch_bounds__(256) void conv6_kernel(
        const u16* __restrict__ xTp, const u16* __restrict__ Wt,
        float* __restrict__ conv_out, float* __restrict__ stats) {
    __shared__ __align__(16) u16 Xh[194 * 128];   // 49,664 B

    int t = threadIdx.x;
    int pt = blockIdx.x, b = blockIdx.y, j = blockIdx.z;
    int p0 = pt * 128;
    int w = t >> 6, lane = t & 63;
    int q = lane >> 4, l16 = lane & 15;
    int cobase = (w & 1) * 64;
    int pixbase = (w >> 1) * 64;

    const u16* xb  = xTp + ((size_t)b * XROWS + 64) * 128;  // row 0 = pixel 0
    const u16* wjb = Wt + (size_t)j * 9 * 16384;

    // ---- stage Xh rows [p0-33, p0+161), unconditional (guard rows) ----
#pragma unroll
    for (int k = 0; k < 13; ++k) {
        int c = t + k * 256;
        if (c < 194 * 16) {
            int row = c >> 4, seg = c & 15;
            int pg = p0 - 33 + row;
            uint4 v = *(const uint4*)(xb + (size_t)pg * 128 + seg * 8);
            *(uint4*)&Xh[row * 128 + ((seg + row) & 15) * 8] = v;
        }
    }
    __syncthreads();     // the only barrier in the kernel

    f32x4 acc[4][4];
#pragma unroll
    for (int mt = 0; mt < 4; ++mt)
#pragma unroll
        for (int nt = 0; nt < 4; ++nt) acc[mt][nt] = (f32x4)0.f;

    for (int tap = 0; tap < 9; ++tap) {
        int dy = tap / 3, dx = tap % 3;
        bool inv_e = (dx == 0) && (l16 == 0);    // nt even: px%32 == l16
        bool inv_o = (dx == 2) && (l16 == 15);   // nt odd:  px%32 == 16+l16
        int rbase = pixbase + dy * 32 + dx + l16;
        const u16* wt = wjb + tap * 16384;
#pragma unroll
        for (int ks = 0; ks < 4; ++ks) {
            int k0 = ks * 32 + q * 8;
            int sl = ks * 4 + q;                 // logical k-segment
            short8 a[4], bf[4];
#pragma unroll
            for (int mt = 0; mt < 4; ++mt)
                a[mt] = *(const short8*)(wt
                        + (size_t)(cobase + mt * 16 + l16) * 128 + k0);
#pragma unroll
            for (int nt = 0; nt < 4; ++nt) {
                int row = rbase + nt * 16;
                short8 v = *(const short8*)&Xh[row * 128
                                               + ((sl + row) & 15) * 8];
                bf[nt] = ((nt & 1) ? inv_o : inv_e) ? (short8)0 : v;
            }
#pragma unroll
            for (int mt = 0; mt < 4; ++mt)
#pragma unroll
                for (int nt = 0; nt < 4; ++nt)
                    acc[mt][nt] = __builtin_amdgcn_mfma_f32_16x16x32_bf16(
                        a[mt], bf[nt], acc[mt][nt], 0, 0, 0);
        }
    }

    // ---- epilogue: conv_out [j*16+b][co][pix] fp32 + stats (proven) ----
    float s = 0.f, s2 = 0.f;
    size_t obase = ((size_t)(j * NB + b) * NC) * NPIX;
#pragma unroll
    for (int mt = 0; mt < 4; ++mt) {
#pragma unroll
        for (int nt = 0; nt < 4; ++nt) {
            f32x4 v = acc[mt][nt];
            int co  = cobase + mt * 16 + q * 4;
            int pix = p0 + pixbase + nt * 16 + l16;
#pragma unroll
            for (int r = 0; r < 4; ++r) {
                float val = v[r];
                conv_out[obase + (size_t)(co + r) * NPIX + pix] = val;
                s += val;
                s2 = fmaf(val, val, s2);
            }
        }
    }
#pragma unroll
    for (int off = 32; off; off >>= 1) {
        s  += __shfl_down(s,  (unsigned)off, 64);
        s2 += __shfl_down(s2, (unsigned)off, 64);
    }
    if (lane == 0) {
        atomicAdd(&stats[(j * NB + b) * 2 + 0], s);
        atomicAdd(&stats[(j * NB + b) * 2 + 1], s2);
    }
}

// ---------------------------------------------------------------------------
// norm_kernel: GroupNorm(1) + exact GELU. Outputs f16 (proven round 7).
// flag dispatch removed -> per-wave self-detect from x.
// ---------------------------------------------------------------------------
__global__ __launch_bounds__(256) void norm_kernel(
        const void* __restrict__ xdet,
        const float* __restrict__ conv_out, const float* __restrict__ stats,
        const void* __restrict__ g0, const void* __restrict__ b0,
        const void* __restrict__ g1, const void* __restrict__ b1,
        const void* __restrict__ g2, const void* __restrict__ b2,
        u16* __restrict__ qh, u16* __restrict__ kh, u16* __restrict__ vh) {
    __shared__ float tile[32 * 257];
    int isf = detect_isf(xdet);
    int t = threadIdx.x;
    int n0 = blockIdx.x * 256;
    int h = blockIdx.y;
    int z = blockIdx.z;
    int j = z >> 4;
    int b = z & 15;
    const void* gam = (j == 0) ? g0 : ((j == 1) ? g1 : g2);
    const void* bet = (j == 0) ? b0 : ((j == 1) ? b1 : b2);

    float sum = stats[z * 2], ss = stats[z * 2 + 1];
    const float inv = 1.0f / 131072.0f;
    float mean = sum * inv;
    float var  = fmaxf(ss * inv - mean * mean, 0.f);
    float rstd = rsqrtf(var + 1e-6f);

    const float* src = conv_out + ((size_t)z * NC + h * DH) * NPIX + n0;

    if (j == 2) {
        u16* dst = vh + (((size_t)(b * NH + h)) * DH) * NPIX + n0;
#pragma unroll
        for (int cl = 0; cl < 32; ++cl) {
            float v = src[cl * NPIX + t];
            v = (v - mean) * rstd * loadf(gam, h * DH + cl, isf)
              + loadf(bet, h * DH + cl, isf);
            v = 0.5f * v * (1.0f + erff(v * 0.70710678118654752f));
            dst[(size_t)cl * NPIX + t] = f2h(v);
        }
        return;
    }

#pragma unroll
    for (int cl = 0; cl < 32; ++cl) tile[cl * 257 + t] = src[cl * NPIX + t];
    __syncthreads();

    u16* dst = ((j == 0) ? qh : kh)
             + (((size_t)(b * NH + h)) * NPIX + n0) * DH;
#pragma unroll
    for (int k = 0; k < 32; ++k) {
        int o = t + k * 256;
        int d = o & 31, nl = o >> 5;
        float v = tile[d * 257 + nl];
        v = (v - mean) * rstd * loadf(gam, h * DH + d, isf)
          + loadf(bet, h * DH + d, isf);
        v = 0.5f * v * (1.0f + erff(v * 0.70710678118654752f));
        dst[o] = f2h(v);
    }
}

// ---------------------------------------------------------------------------
// attn2: MFMA flash attention, zero LDS (proven round 7/8).
// ---------------------------------------------------------------------------
__global__ __launch_bounds__(256) void attn2_kernel(
        const u16* __restrict__ qh, const u16* __restrict__ kh,
        const u16* __restrict__ vh, const u16* __restrict__ biasT,
        u16* __restrict__ attfh) {
    int t = threadIdx.x;
    int b = blockIdx.x, h = blockIdx.y, qt = blockIdx.z;
    int w = t >> 6, lane = t & 63, q = lane >> 4, l16 = lane & 15;
    int nrow0 = qt * 128 + w * 32;

    const u16* qb = qh + (((size_t)(b * NH + h)) * NPIX) * DH;
    const u16* kb = kh + (((size_t)(b * NH + h)) * NPIX) * DH;
    const u16* vb = vh + (((size_t)(b * NH + h)) * DH) * NPIX;
    const u16* bb = biasT + ((size_t)h << 20);

    half8 qf[2];
#pragma unroll
    for (int nt = 0; nt < 2; ++nt)
        qf[nt] = *(const half8*)(qb + (size_t)(nrow0 + nt * 16 + l16) * DH
                                 + q * 8);

    f32x4 O[2][2];   // [dt][nt], O^T C-layout: col n=l16, row d=q*4+reg
#pragma unroll
    for (int dt = 0; dt < 2; ++dt)
#pragma unroll
        for (int nt = 0; nt < 2; ++nt) O[dt][nt] = (f32x4)0.f;
    float mrow[2] = {-1e30f, -1e30f}, lrow[2] = {0.f, 0.f};

    int addrLo = ((2 * (q & 1)) * 16 + l16) * 4;
    int addrHi = addrLo + 64;
    bool hiQ = (q >= 2);

    for (int kc = 0; kc < 8; ++kc) {
        int m0 = kc * 128;
        f32x4 St[8][2];
#pragma unroll
        for (int mt = 0; mt < 8; ++mt) {
            half8 kf = *(const half8*)(kb + (size_t)(m0 + mt * 16 + l16) * DH
                                       + q * 8);
            St[mt][0] = __builtin_amdgcn_mfma_f32_16x16x32_f16(
                kf, qf[0], (f32x4)0.f, 0, 0, 0);
            St[mt][1] = __builtin_amdgcn_mfma_f32_16x16x32_f16(
                kf, qf[1], (f32x4)0.f, 0, 0, 0);
        }
        float mx[2] = {-1e30f, -1e30f};
#pragma unroll
        for (int mt = 0; mt < 8; ++mt)
#pragma unroll
            for (int nt = 0; nt < 2; ++nt) {
                const u16* bp = bb + (size_t)(m0 + mt * 16 + q * 4) * 1024
                              + nrow0 + nt * 16 + l16;
#pragma unroll
                for (int r = 0; r < 4; ++r) {
                    float v = St[mt][nt][r] + bf2f(bp[(size_t)r * 1024]);
                    St[mt][nt][r] = v;
                    mx[nt] = fmaxf(mx[nt], v);
                }
            }
        float alpha[2];
#pragma unroll
        for (int nt = 0; nt < 2; ++nt) {
            mx[nt] = fmaxf(mx[nt], __shfl_xor(mx[nt], 16, 64));
            mx[nt] = fmaxf(mx[nt], __shfl_xor(mx[nt], 32, 64));
            float mn = fmaxf(mrow[nt], mx[nt]);
            alpha[nt] = __expf(mrow[nt] - mn);
            mrow[nt] = mn;
        }
        float sm[2] = {0.f, 0.f};
#pragma unroll
        for (int mt = 0; mt < 8; ++mt)
#pragma unroll
            for (int nt = 0; nt < 2; ++nt)
#pragma unroll
                for (int r = 0; r < 4; ++r) {
                    float p = __expf(St[mt][nt][r] - mrow[nt]);
                    St[mt][nt][r] = p;
                    sm[nt] += p;
                }
#pragma unroll
        for (int nt = 0; nt < 2; ++nt) {
            sm[nt] += __shfl_xor(sm[nt], 16, 64);
            sm[nt] += __shfl_xor(sm[nt], 32, 64);
            lrow[nt] = lrow[nt] * alpha[nt] + sm[nt];
        }
#pragma unroll
        for (int dt = 0; dt < 2; ++dt)
#pragma unroll
            for (int nt = 0; nt < 2; ++nt)
#pragma unroll
                for (int r = 0; r < 4; ++r)
                    O[dt][nt][r] *= alpha[nt];
#pragma unroll
        for (int ms = 0; ms < 4; ++ms) {
            half8 vf[2];
#pragma unroll
            for (int dt = 0; dt < 2; ++dt)
                vf[dt] = *(const half8*)(vb + (size_t)(dt * 16 + l16) * NPIX
                                         + m0 + ms * 32 + q * 8);
#pragma unroll
            for (int nt = 0; nt < 2; ++nt) {
                int p01_0 = pk_h2(St[2 * ms][nt][0],     St[2 * ms][nt][1]);
                int p23_0 = pk_h2(St[2 * ms][nt][2],     St[2 * ms][nt][3]);
                int p01_1 = pk_h2(St[2 * ms + 1][nt][0], St[2 * ms + 1][nt][1]);
                int p23_1 = pk_h2(St[2 * ms + 1][nt][2], St[2 * ms + 1][nt][3]);
                // FULL-EXEC bpermutes, then per-dest select (round-7 fix).
                int a0 = __builtin_amdgcn_ds_bpermute(addrLo, p01_0);
                int a1 = __builtin_amdgcn_ds_bpermute(addrLo, p23_0);
                int a2 = __builtin_amdgcn_ds_bpermute(addrHi, p01_0);
                int a3 = __builtin_amdgcn_ds_bpermute(addrHi, p23_0);
                int b0 = __builtin_amdgcn_ds_bpermute(addrLo, p01_1);
                int b1 = __builtin_amdgcn_ds_bpermute(addrLo, p23_1);
                int b2 = __builtin_amdgcn_ds_bpermute(addrHi, p01_1);
                int b3 = __builtin_amdgcn_ds_bpermute(addrHi, p23_1);
                int pb[4];
                pb[0] = hiQ ? b0 : a0;
                pb[1] = hiQ ? b1 : a1;
                pb[2] = hiQ ? b2 : a2;
                pb[3] = hiQ ? b3 : a3;
                half8 pf; __builtin_memcpy(&pf, pb, 16);
#pragma unroll
                for (int dt = 0; dt < 2; ++dt)
                    O[dt][nt] = __builtin_amdgcn_mfma_f32_16x16x32_f16(
                        vf[dt], pf, O[dt][nt], 0, 0, 0);
            }
        }
    }

    // ---- epilogue: attfh[b][n][c] f16 (8B packed stores) ----
#pragma unroll
    for (int nt = 0; nt < 2; ++nt) {
        float rl = 1.0f / lrow[nt];
        int n = nrow0 + nt * 16 + l16;
        u16* dst = attfh + ((size_t)b * NPIX + n) * NC + h * DH;
#pragma unroll
        for (int dt = 0; dt < 2; ++dt) {
            f32x4 o = O[dt][nt];
            uint2 pv = make_uint2((u32)pk_h2(o[0] * rl, o[1] * rl),
                                  (u32)pk_h2(o[2] * rl, o[3] * rl));
            *(uint2*)(dst + dt * 16 + q * 4) = pv;
        }
    }
}

// ---------------------------------------------------------------------------
// out3: MFMA 1x1 conv + bias, zero LDS (proven round 8). Self-detect.
// ---------------------------------------------------------------------------
__global__ __launch_bounds__(256) void out3_kernel(
        const void* __restrict__ xdet,
        const u16* __restrict__ attfh, const u16* __restrict__ Wf,
        const void* __restrict__ ob, void* __restrict__ out) {
    int isf = detect_isf(xdet);
    int t = threadIdx.x;
    int n0 = blockIdx.x * 64, b = blockIdx.y;
    int w = t >> 6, lane = t & 63, q = lane >> 4, l16 = lane & 15;
    int cobase = (w & 1) * 64, nbase = (w >> 1) * 32;

    f32x4 acc[4][2];
#pragma unroll
    for (int mt = 0; mt < 4; ++mt)
#pragma unroll
        for (int nt = 0; nt < 2; ++nt) acc[mt][nt] = (f32x4)0.f;

    const u16* ab = attfh + ((size_t)b * NPIX + n0 + nbase) * NC;
#pragma unroll
    for (int ks = 0; ks < 4; ++ks) {
        int k0 = ks * 32 + q * 8;
        half8 a[4], bfr[2];
#pragma unroll
        for (int mt = 0; mt < 4; ++mt)
            a[mt] = *(const half8*)(Wf + (size_t)(cobase + mt * 16 + l16) * NC
                                    + k0);
#pragma unroll
        for (int nt = 0; nt < 2; ++nt)
            bfr[nt] = *(const half8*)(ab + (size_t)(nt * 16 + l16) * NC + k0);
#pragma unroll
        for (int mt = 0; mt < 4; ++mt)
#pragma unroll
            for (int nt = 0; nt < 2; ++nt)
                acc[mt][nt] = __builtin_amdgcn_mfma_f32_16x16x32_f16(
                    a[mt], bfr[nt], acc[mt][nt], 0, 0, 0);
    }

#pragma unroll
    for (int mt = 0; mt < 4; ++mt) {
#pragma unroll
        for (int nt = 0; nt < 2; ++nt) {
            f32x4 v = acc[mt][nt];
            int n = n0 + nbase + nt * 16 + l16;
#pragma unroll
            for (int r = 0; r < 4; ++r) {
                int co = cobase + mt * 16 + q * 4 + r;
                float val = v[r] + loadf(ob, co, isf);
                size_t oidx = ((size_t)b * NC + co) * NPIX + n;
                if (isf) ((float*)out)[oidx] = val;
                else     ((u16*)out)[oidx]   = f2bf(val);
            }
        }
    }
}

// ---------------------------------------------------------------------------
// Workspace (peak ~48 MiB). biasT now written BEFORE conv (prep_all), so it
// moved out of the conv-aliased region:
//   [0,448) stats (zeroed by prep_all block 0) | [448,512) pad
//   regQ = ws+512 (25,165,824 B):
//     xTp  bf16 4,718,592 B  @Q+0          (prep_all -> conv6; dead after)
//     Wt   bf16   884,736 B  @Q+5242880    (prep_all -> conv6; dead after)
//     qh/kh/vh f16 4 MB each @Q+0/4M/8M    (norm -> attn2; overwrite xTp/Wt)
//     biasT bf16 8 MB        @Q+12582912   (prep_all -> attn2)  [12M,20M)
//     Wf    f16 32 KB        @Q+20971520   (prep_all -> out3)
//   regA = regQ+25165824 (25,165,824 B):
//     conv fp32 25 MB                      (conv6 -> norm; dead after)
//     attfh f16 4 MB @A+8388608            (attn2 -> out3, aliases dead conv)
// 5 dispatches: prep_all -> conv6 -> norm -> attn2 -> out3
// ---------------------------------------------------------------------------
extern "C" void kernel_launch(void* const* d_in, const int* in_sizes, int n_in,
                              void* d_out, int out_size, void* d_ws,
                              size_t ws_size, hipStream_t stream) {
    (void)in_sizes; (void)n_in; (void)out_size; (void)ws_size;
    const void* x     = d_in[0];
    const void* wq    = d_in[1];
    const void* gq    = d_in[2];
    const void* bq    = d_in[3];
    const void* wk    = d_in[4];
    const void* gk    = d_in[5];
    const void* bk    = d_in[6];
    const void* wv    = d_in[7];
    const void* gv    = d_in[8];
    const void* bv    = d_in[9];
    const void* table = d_in[10];
    const int*  rel   = (const int*)d_in[11];
    const void* ow    = d_in[12];
    const void* ob    = d_in[13];

    char* ws = (char*)d_ws;
    float* stats = (float*)(ws);
    char*  regQ  = ws + 512;
    u16*   xTp   = (u16*)regQ;                       // padded, 4,718,592 B
    u16*   Wt    = (u16*)(regQ + 5242880);
    u16*   qhp   = (u16*)regQ;                       // alias after conv6
    u16*   khp   = (u16*)(regQ + 4194304);
    u16*   vhp   = (u16*)(regQ + 8388608);
    u16*   biasT = (u16*)(regQ + 12582912);          // prep_all -> attn2
    u16*   Wf    = (u16*)(regQ + 20971520);          // prep_all -> out3
    char*  regA  = regQ + 25165824;
    float* conv  = (float*)regA;                     // conv6 -> norm
    u16*   attfh = (u16*)(regA + 8388608);           // attn2 -> out3 (f16)

    prep_all<<<2560, 256, 0, stream>>>(x, wq, wk, wv, ow, rel, table,
                                       Wt, Wf, xTp, biasT, stats);
    conv6_kernel<<<dim3(8, 16, 3), 256, 0, stream>>>(xTp, Wt, conv, stats);
    norm_kernel<<<dim3(4, 4, 48), 256, 0, stream>>>(x, conv, stats,
                                                    gq, bq, gk, bk, gv, bv,
                                                    qhp, khp, vhp);
    attn2_kernel<<<dim3(16, 4, 8), 256, 0, stream>>>(qhp, khp, vhp, biasT,
                                                     attfh);
    out3_kernel<<<dim3(16, 16), 256, 0, stream>>>(x, attfh, Wf, ob, d_out);
}